// Round 6
// baseline (132.228 us; speedup 1.0000x reference)
//
#include <hip/hip_runtime.h>
#include <hip/hip_bf16.h>
#include <stdint.h>

#define NROWS 8192
#define DIM   512
#define NQ    16           // 32-wide k-frags per panel (DIM/32)
#define NSTEP 8            // K-steps (BK=64)

typedef unsigned short u16;
typedef short bf16x8 __attribute__((ext_vector_type(8)));
typedef float f32x4  __attribute__((ext_vector_type(4)));
typedef unsigned short u16x8 __attribute__((ext_vector_type(8)));

// ---- order-preserving float<->uint encoding for atomicMax on floats ----
__device__ __forceinline__ unsigned fenc(float f) {
  unsigned u = __float_as_uint(f);
  return (u & 0x80000000u) ? ~u : (u | 0x80000000u);
}
__device__ __forceinline__ float fdec(unsigned u) {
  unsigned b = (u & 0x80000000u) ? (u ^ 0x80000000u) : ~u;
  return __uint_as_float(b);
}

// RNE f32 -> bf16 (no NaN inputs here)
__device__ __forceinline__ u16 f2bf(float x) {
  unsigned u = __float_as_uint(x);
  u += 0x7FFFu + ((u >> 16) & 1u);
  return (u16)(u >> 16);
}

__device__ __forceinline__ void async16(const void* g, void* l) {
  __builtin_amdgcn_global_load_lds(
      (const __attribute__((address_space(1))) unsigned int*)g,
      (__attribute__((address_space(3))) unsigned int*)l, 16, 0, 0);
}

// ---- normalize 16 rows (one panel) -> bf16 in FRAGMENT-MAJOR layout ----
// Fragment (panel P, q): 1KB at (P*NQ+q)*512 ushorts; lane l holds
// row P*16+(l&15), k = q*32 + (l>>4)*8 + j, stored at lane*8+j.
// One fused launch handles both inputs (blockIdx 0..511 -> ex, 512.. -> ey)
// and initializes the encoded max arrays from the first 32 blocks.
__global__ __launch_bounds__(512) void normf_kernel(
    const float* __restrict__ ex, const float* __restrict__ ey,
    u16* __restrict__ Xf, u16* __restrict__ Yf,
    unsigned* __restrict__ enc_init) {
  const int pb = blockIdx.x;
  const int p = pb & 511;
  const float* src = (pb < 512) ? ex : ey;
  u16* dst = (pb < 512) ? Xf : Yf;
  const int t = threadIdx.x, lane = t & 63, w = t >> 6;
  const int fr = lane & 15, hi = lane >> 4;
  if (pb < 32) {
    enc_init[pb * 512 + t] = fenc(-2.0f);
  }
  __shared__ float part[16][8];
  float e[2][8];
  float ss = 0.f;
#pragma unroll
  for (int c = 0; c < 2; ++c) {
    const int q = w + c * 8;
    const float* g = src + (size_t)(p * 16 + fr) * DIM + q * 32 + hi * 8;
    float4 v0 = *(const float4*)g;
    float4 v1 = *(const float4*)(g + 4);
    e[c][0] = v0.x; e[c][1] = v0.y; e[c][2] = v0.z; e[c][3] = v0.w;
    e[c][4] = v1.x; e[c][5] = v1.y; e[c][6] = v1.z; e[c][7] = v1.w;
#pragma unroll
    for (int j = 0; j < 8; ++j) ss += e[c][j] * e[c][j];
  }
  ss += __shfl_xor(ss, 16);
  ss += __shfl_xor(ss, 32);
  if (lane < 16) part[lane][w] = ss;
  __syncthreads();
  float tot = 0.f;
#pragma unroll
  for (int i = 0; i < 8; ++i) tot += part[fr][i];
  const float sc = 1.0f / fmaxf(sqrtf(tot), 1e-8f);
#pragma unroll
  for (int c = 0; c < 2; ++c) {
    const int q = w + c * 8;
    u16x8 o;
#pragma unroll
    for (int j = 0; j < 8; ++j) o[j] = f2bf(e[c][j] * sc);
    *(u16x8*)(dst + ((size_t)(p * NQ + q) * 64 + lane) * 8) = o;
  }
}

// ---- 128x128 MFMA GEMM, m97 skeleton: BK=64, single buffer, 2 syncs ----
__global__ __launch_bounds__(256) void gemm_max_kernel(
    const u16* __restrict__ Xf, const u16* __restrict__ Yf,
    unsigned* __restrict__ rowmax, unsigned* __restrict__ colmax) {
  // fragment-major single buffer: f 0..15 = A(panel 0..7 x kk 0..1),
  // f 16..31 = B. 32 KB.
  __shared__ u16 lds[32][512];

  const int t = threadIdx.x, lane = t & 63, w = t >> 6;
  const int wr = w >> 1, wc = w & 1;  // 2x2 wave grid; wave owns 64x64 out

  // bijective XCD swizzle: 4096 blocks; per XCD an 8x8 supertile of
  // 128x128 tiles (A 2MB + B 2MB -> L2-friendly).
  const int raw = blockIdx.x, xcd = raw & 7, l = raw >> 3;  // l: 0..511
  const int brow = ((l >> 6) * 8 + (l & 7)) * 128;
  const int bcol = (xcd * 8 + ((l >> 3) & 7)) * 128;
  const int browP = brow >> 4, bcolP = bcol >> 4;

  f32x4 acc[4][4];
#pragma unroll
  for (int m = 0; m < 4; ++m)
#pragma unroll
    for (int n = 0; n < 4; ++n) acc[m][n] = (f32x4){0.f, 0.f, 0.f, 0.f};

  // staging: wave w stages A panels {2w,2w+1} and B panels {2w,2w+1},
  // both kk, 1 KB contiguous per async16 (8 per wave per step).
  const u16* gA0 = Xf + ((size_t)(browP + 2 * w) * NQ) * 512 + lane * 8;
  const u16* gA1 = Xf + ((size_t)(browP + 2 * w + 1) * NQ) * 512 + lane * 8;
  const u16* gB0 = Yf + ((size_t)(bcolP + 2 * w) * NQ) * 512 + lane * 8;
  const u16* gB1 = Yf + ((size_t)(bcolP + 2 * w + 1) * NQ) * 512 + lane * 8;

#pragma unroll 1
  for (int h = 0; h < NSTEP; ++h) {
    const size_t o = (size_t)h * 2 * 512;  // k-frag pair base for this step
    __syncthreads();  // previous compute done -> buffer reusable
#pragma unroll
    for (int kk = 0; kk < 2; ++kk) {
      async16(gA0 + o + kk * 512, &lds[(2 * w) * 2 + kk][0]);
      async16(gA1 + o + kk * 512, &lds[(2 * w + 1) * 2 + kk][0]);
      async16(gB0 + o + kk * 512, &lds[16 + (2 * w) * 2 + kk][0]);
      async16(gB1 + o + kk * 512, &lds[16 + (2 * w + 1) * 2 + kk][0]);
    }
    __syncthreads();  // compiler drains vmcnt before barrier -> data ready
#pragma unroll
    for (int kk = 0; kk < 2; ++kk) {
      bf16x8 a[4], b[4];
#pragma unroll
      for (int n = 0; n < 4; ++n)
        b[n] = *(const bf16x8*)(&lds[16 + (wc * 4 + n) * 2 + kk][lane * 8]);
#pragma unroll
      for (int m = 0; m < 4; ++m)
        a[m] = *(const bf16x8*)(&lds[(wr * 4 + m) * 2 + kk][lane * 8]);
#pragma unroll
      for (int m = 0; m < 4; ++m)
#pragma unroll
        for (int n = 0; n < 4; ++n)
          acc[m][n] = __builtin_amdgcn_mfma_f32_16x16x32_bf16(a[m], b[n], acc[m][n], 0, 0, 0);
    }
  }

  // ---- epilogue: C/D layout col=lane&15, row=(lane>>4)*4+reg ----
#pragma unroll
  for (int m = 0; m < 4; ++m) {
    f32x4 rm = acc[m][0];
#pragma unroll
    for (int n = 1; n < 4; ++n) {
      rm[0] = fmaxf(rm[0], acc[m][n][0]);
      rm[1] = fmaxf(rm[1], acc[m][n][1]);
      rm[2] = fmaxf(rm[2], acc[m][n][2]);
      rm[3] = fmaxf(rm[3], acc[m][n][3]);
    }
#pragma unroll
    for (int r = 0; r < 4; ++r) {
      float v = rm[r];
      v = fmaxf(v, __shfl_xor(v, 1));
      v = fmaxf(v, __shfl_xor(v, 2));
      v = fmaxf(v, __shfl_xor(v, 4));
      v = fmaxf(v, __shfl_xor(v, 8));
      if ((lane & 15) == 0) {
        const int grow = brow + wr * 64 + m * 16 + (lane >> 4) * 4 + r;
        atomicMax(rowmax + grow, fenc(v));
      }
    }
  }
#pragma unroll
  for (int n = 0; n < 4; ++n) {
    float cm = -2.0f;
#pragma unroll
    for (int m = 0; m < 4; ++m) {
      cm = fmaxf(cm, acc[m][n][0]);
      cm = fmaxf(cm, acc[m][n][1]);
      cm = fmaxf(cm, acc[m][n][2]);
      cm = fmaxf(cm, acc[m][n][3]);
    }
    cm = fmaxf(cm, __shfl_xor(cm, 16));
    cm = fmaxf(cm, __shfl_xor(cm, 32));
    if (lane < 16) {
      const int gcol = bcol + wc * 64 + n * 16 + lane;
      atomicMax(colmax + gcol, fenc(cm));
    }
  }
}

// ---- entropy: out[b] = -sum( exp(lp)*lp ), lp = -0.5*z^2 + 0.285034... ----
__global__ __launch_bounds__(256) void entropy_kernel(
    const unsigned* __restrict__ enc, float* __restrict__ out) {
  const int which = blockIdx.x;
  const unsigned* e = enc + which * NROWS;
  float s = 0.0f;
  for (int i = threadIdx.x; i < NROWS; i += 256) {
    const float x = fdec(e[i]);
    const float z = (x - 1.0f) * (1.0f / 0.3f);
    const float lp = -0.5f * z * z + 0.2850342711439819f;
    s += expf(lp) * lp;
  }
#pragma unroll
  for (int m = 1; m <= 32; m <<= 1) s += __shfl_xor(s, m);
  __shared__ float sr[4];
  if ((threadIdx.x & 63) == 0) sr[threadIdx.x >> 6] = s;
  __syncthreads();
  if (threadIdx.x == 0) out[which] = -(sr[0] + sr[1] + sr[2] + sr[3]);
}

extern "C" void kernel_launch(void* const* d_in, const int* in_sizes, int n_in,
                              void* d_out, int out_size, void* d_ws, size_t ws_size,
                              hipStream_t stream) {
  const float* ex = (const float*)d_in[0];
  const float* ey = (const float*)d_in[1];

  u16* Xf = (u16*)d_ws;                                  // 8 MB fragment-major
  u16* Yf = Xf + (size_t)NROWS * DIM;                    // 8 MB
  unsigned* enc = (unsigned*)(Yf + (size_t)NROWS * DIM); // 2*8192 u32
  float* out = (float*)d_out;

  hipLaunchKernelGGL(normf_kernel, dim3(1024), dim3(512), 0, stream,
                     ex, ey, Xf, Yf, enc);
  hipLaunchKernelGGL(gemm_max_kernel, dim3(64 * 64), dim3(256), 0, stream,
                     Xf, Yf, enc, enc + NROWS);
  hipLaunchKernelGGL(entropy_kernel, dim3(2), dim3(256), 0, stream, enc, out);
}

// Round 7
// 96.365 us; speedup vs baseline: 1.3722x; 1.3722x over previous
//
#include <hip/hip_runtime.h>
#include <hip/hip_bf16.h>
#include <stdint.h>

#define NROWS 8192
#define DIM   512
#define NQ    16           // 32-wide k-frags per panel (DIM/32)
#define NSTEP 8            // K-steps (BK=64)
#define FSCALE 16.0f       // fp8 pre-scale (power of 2); C is scaled by 256
#define INV_FS2 (1.0f / 256.0f)

typedef unsigned char u8;
typedef long i64;
typedef float f32x4 __attribute__((ext_vector_type(4)));

// ---- order-preserving float<->uint encoding for atomicMax on floats ----
__device__ __forceinline__ unsigned fenc(float f) {
  unsigned u = __float_as_uint(f);
  return (u & 0x80000000u) ? ~u : (u | 0x80000000u);
}
__device__ __forceinline__ float fdec(unsigned u) {
  unsigned b = (u & 0x80000000u) ? (u ^ 0x80000000u) : ~u;
  return __uint_as_float(b);
}

// ---- f32 -> fp8 e4m3fn (OCP) ----
#if __has_builtin(__builtin_amdgcn_cvt_pk_fp8_f32)
#define HAVE_CVT_PK_FP8 1
#else
// manual RNE fallback (FTZ below 2^-6; clamp to 448)
__device__ __forceinline__ u8 f2e4m3(float f) {
  unsigned u = __float_as_uint(f);
  unsigned sgn = (u >> 24) & 0x80u;
  unsigned au = u & 0x7FFFFFFFu;
  if (au < 0x3C800000u) return (u8)sgn;            // |f| < 2^-6 -> 0
  unsigned r = au + 0x7FFFFu + ((au >> 20) & 1u);  // RNE to 3 mantissa bits
  int e = (int)((r >> 23) & 0xFF) - 127;
  unsigned m = (r >> 20) & 7u;
  if (e > 8) return (u8)(sgn | 0x7Eu);             // clamp to 448
  return (u8)(sgn | ((unsigned)(e + 7) << 3) | m);
}
#endif

__device__ __forceinline__ void async16(const void* g, void* l) {
  __builtin_amdgcn_global_load_lds(
      (const __attribute__((address_space(1))) unsigned int*)g,
      (__attribute__((address_space(3))) unsigned int*)l, 16, 0, 0);
}

// ---- normalize 16 rows (one panel) -> fp8 in FRAGMENT-MAJOR layout ----
// Fragment (panel P, q): 512B at (P*NQ+q)*512 bytes; lane l holds 8 fp8 at
// byte lane*8: row P*16+(l&15), k = q*32+(l>>4)*8+j, value = xn*FSCALE.
// One fused launch: blockIdx 0..511 -> ex, 512.. -> ey; first 32 blocks
// also init the encoded max arrays.
__global__ __launch_bounds__(512) void normf_kernel(
    const float* __restrict__ ex, const float* __restrict__ ey,
    u8* __restrict__ Xf, u8* __restrict__ Yf,
    unsigned* __restrict__ enc_init) {
  const int pb = blockIdx.x;
  const int p = pb & 511;
  const float* src = (pb < 512) ? ex : ey;
  u8* dst = (pb < 512) ? Xf : Yf;
  const int t = threadIdx.x, lane = t & 63, w = t >> 6;
  const int fr = lane & 15, hi = lane >> 4;
  if (pb < 32) {
    enc_init[pb * 512 + t] = fenc(-512.0f);  // below min possible scaled C
  }
  __shared__ float part[16][8];
  float e[2][8];
  float ss = 0.f;
#pragma unroll
  for (int c = 0; c < 2; ++c) {
    const int q = w + c * 8;
    const float* g = src + (size_t)(p * 16 + fr) * DIM + q * 32 + hi * 8;
    float4 v0 = *(const float4*)g;
    float4 v1 = *(const float4*)(g + 4);
    e[c][0] = v0.x; e[c][1] = v0.y; e[c][2] = v0.z; e[c][3] = v0.w;
    e[c][4] = v1.x; e[c][5] = v1.y; e[c][6] = v1.z; e[c][7] = v1.w;
#pragma unroll
    for (int j = 0; j < 8; ++j) ss += e[c][j] * e[c][j];
  }
  ss += __shfl_xor(ss, 16);
  ss += __shfl_xor(ss, 32);
  if (lane < 16) part[lane][w] = ss;
  __syncthreads();
  float tot = 0.f;
#pragma unroll
  for (int i = 0; i < 8; ++i) tot += part[fr][i];
  const float sc = FSCALE / fmaxf(sqrtf(tot), 1e-8f);
#pragma unroll
  for (int c = 0; c < 2; ++c) {
    const int q = w + c * 8;
#if HAVE_CVT_PK_FP8
    int lo = 0, hi2 = 0;
    lo = __builtin_amdgcn_cvt_pk_fp8_f32(e[c][0] * sc, e[c][1] * sc, lo, false);
    lo = __builtin_amdgcn_cvt_pk_fp8_f32(e[c][2] * sc, e[c][3] * sc, lo, true);
    hi2 = __builtin_amdgcn_cvt_pk_fp8_f32(e[c][4] * sc, e[c][5] * sc, hi2, false);
    hi2 = __builtin_amdgcn_cvt_pk_fp8_f32(e[c][6] * sc, e[c][7] * sc, hi2, true);
    const unsigned long long pk =
        (unsigned long long)(unsigned)lo | ((unsigned long long)(unsigned)hi2 << 32);
#else
    unsigned long long pk = 0;
#pragma unroll
    for (int j = 0; j < 8; ++j)
      pk |= (unsigned long long)f2e4m3(e[c][j] * sc) << (8 * j);
#endif
    *(unsigned long long*)(dst + (size_t)(p * NQ + q) * 512 + lane * 8) = pk;
  }
}

// ---- 128x128 fp8 MFMA GEMM, 2-slot ring, BK=64, fused row/col max ----
// LDS slot (16 KB): frags 0..15 = A (panel 0..7 x kk 0..1), 16..31 = B.
__global__ __launch_bounds__(256, 4) void gemm_max_kernel(
    const u8* __restrict__ Xf, const u8* __restrict__ Yf,
    unsigned* __restrict__ rowmax, unsigned* __restrict__ colmax) {
  __shared__ u8 lds[2][32][512];  // 32 KB

  const int t = threadIdx.x, lane = t & 63, w = t >> 6;
  const int wr = w >> 1, wc = w & 1;  // 2x2 wave grid; wave owns 64x64 out

  // bijective XCD swizzle: 4096 blocks; per XCD an 8x8 supertile of tiles
  const int raw = blockIdx.x, xcd = raw & 7, l = raw >> 3;  // l: 0..511
  const int brow = ((l >> 6) * 8 + (l & 7)) * 128;
  const int bcol = (xcd * 8 + ((l >> 3) & 7)) * 128;
  const int browP = brow >> 4, bcolP = bcol >> 4;

  f32x4 acc[4][4];
#pragma unroll
  for (int m = 0; m < 4; ++m)
#pragma unroll
    for (int n = 0; n < 4; ++n) acc[m][n] = (f32x4){0.f, 0.f, 0.f, 0.f};

  // staging: wave w stages A panels {2w,2w+1}, B panels {2w,2w+1}.
  // Per step one async16 (1 KB) covers a panel's consecutive kk frag-pair.
  const u8* gA0 = Xf + (size_t)(browP + 2 * w) * (NQ * 512) + lane * 16;
  const u8* gA1 = Xf + (size_t)(browP + 2 * w + 1) * (NQ * 512) + lane * 16;
  const u8* gB0 = Yf + (size_t)(bcolP + 2 * w) * (NQ * 512) + lane * 16;
  const u8* gB1 = Yf + (size_t)(bcolP + 2 * w + 1) * (NQ * 512) + lane * 16;

  auto stage = [&](int h, int s) {
    const size_t o = (size_t)h * 1024;  // kk frag-pair offset within panel
    async16(gA0 + o, &lds[s][4 * w][0]);
    async16(gA1 + o, &lds[s][4 * w + 2][0]);
    async16(gB0 + o, &lds[s][16 + 4 * w][0]);
    async16(gB1 + o, &lds[s][16 + 4 * w + 2][0]);
  };

  stage(0, 0);

  // 1 barrier per K-step; vmcnt(0) covers loads issued one full step ago.
#pragma unroll 2
  for (int h = 0; h < NSTEP; ++h) {
    asm volatile("s_waitcnt vmcnt(0)" ::: "memory");
    __builtin_amdgcn_s_barrier();
    if (h < NSTEP - 1) stage(h + 1, (h + 1) & 1);
    const int s = h & 1;
#pragma unroll
    for (int kk = 0; kk < 2; ++kk) {
      i64 a[4], b[4];
#pragma unroll
      for (int n = 0; n < 4; ++n)
        b[n] = *(const i64*)(&lds[s][16 + (wc * 4 + n) * 2 + kk][lane * 8]);
#pragma unroll
      for (int m = 0; m < 4; ++m)
        a[m] = *(const i64*)(&lds[s][(wr * 4 + m) * 2 + kk][lane * 8]);
#pragma unroll
      for (int m = 0; m < 4; ++m)
#pragma unroll
        for (int n = 0; n < 4; ++n)
          acc[m][n] = __builtin_amdgcn_mfma_f32_16x16x32_fp8_fp8(
              a[m], b[n], acc[m][n], 0, 0, 0);
    }
  }

  // ---- epilogue: C/D layout col=lane&15, row=(lane>>4)*4+reg (scaled) ----
#pragma unroll
  for (int m = 0; m < 4; ++m) {
    f32x4 rm = acc[m][0];
#pragma unroll
    for (int n = 1; n < 4; ++n) {
      rm[0] = fmaxf(rm[0], acc[m][n][0]);
      rm[1] = fmaxf(rm[1], acc[m][n][1]);
      rm[2] = fmaxf(rm[2], acc[m][n][2]);
      rm[3] = fmaxf(rm[3], acc[m][n][3]);
    }
#pragma unroll
    for (int r = 0; r < 4; ++r) {
      float v = rm[r];
      v = fmaxf(v, __shfl_xor(v, 1));
      v = fmaxf(v, __shfl_xor(v, 2));
      v = fmaxf(v, __shfl_xor(v, 4));
      v = fmaxf(v, __shfl_xor(v, 8));
      if ((lane & 15) == 0) {
        const int grow = brow + wr * 64 + m * 16 + (lane >> 4) * 4 + r;
        atomicMax(rowmax + grow, fenc(v));
      }
    }
  }
#pragma unroll
  for (int n = 0; n < 4; ++n) {
    float cm = -512.0f;
#pragma unroll
    for (int m = 0; m < 4; ++m) {
      cm = fmaxf(cm, acc[m][n][0]);
      cm = fmaxf(cm, acc[m][n][1]);
      cm = fmaxf(cm, acc[m][n][2]);
      cm = fmaxf(cm, acc[m][n][3]);
    }
    cm = fmaxf(cm, __shfl_xor(cm, 16));
    cm = fmaxf(cm, __shfl_xor(cm, 32));
    if (lane < 16) {
      const int gcol = bcol + wc * 64 + n * 16 + lane;
      atomicMax(colmax + gcol, fenc(cm));
    }
  }
}

// ---- entropy: out[b] = -sum( exp(lp)*lp ), x = decoded max / FSCALE^2 ----
__global__ __launch_bounds__(256) void entropy_kernel(
    const unsigned* __restrict__ enc, float* __restrict__ out) {
  const int which = blockIdx.x;
  const unsigned* e = enc + which * NROWS;
  float s = 0.0f;
  for (int i = threadIdx.x; i < NROWS; i += 256) {
    const float x = fdec(e[i]) * INV_FS2;
    const float z = (x - 1.0f) * (1.0f / 0.3f);
    const float lp = -0.5f * z * z + 0.2850342711439819f;
    s += expf(lp) * lp;
  }
#pragma unroll
  for (int m = 1; m <= 32; m <<= 1) s += __shfl_xor(s, m);
  __shared__ float sr[4];
  if ((threadIdx.x & 63) == 0) sr[threadIdx.x >> 6] = s;
  __syncthreads();
  if (threadIdx.x == 0) out[which] = -(sr[0] + sr[1] + sr[2] + sr[3]);
}

extern "C" void kernel_launch(void* const* d_in, const int* in_sizes, int n_in,
                              void* d_out, int out_size, void* d_ws, size_t ws_size,
                              hipStream_t stream) {
  const float* ex = (const float*)d_in[0];
  const float* ey = (const float*)d_in[1];

  u8* Xf = (u8*)d_ws;                                    // 4 MB fragment-major fp8
  u8* Yf = Xf + (size_t)NROWS * DIM;                     // 4 MB
  unsigned* enc = (unsigned*)(Yf + (size_t)NROWS * DIM); // 2*8192 u32
  float* out = (float*)d_out;

  hipLaunchKernelGGL(normf_kernel, dim3(1024), dim3(512), 0, stream,
                     ex, ey, Xf, Yf, enc);
  hipLaunchKernelGGL(gemm_max_kernel, dim3(64 * 64), dim3(256), 0, stream,
                     Xf, Yf, enc, enc + NROWS);
  hipLaunchKernelGGL(entropy_kernel, dim3(2), dim3(256), 0, stream, enc, out);
}